// Round 2
// baseline (1185.869 us; speedup 1.0000x reference)
//
#include <hip/hip_runtime.h>

typedef unsigned long long ull;
typedef unsigned int uint;

#define EMPTY_ENTRY 0xFFFFFFFFFFFFFFFFULL

// 32-bit -> 64-bit hash mixer (splitmix64 finalizer)
__device__ __forceinline__ ull mix_key(uint x) {
    ull h = (ull)x * 0x9E3779B97F4A7C15ULL;
    h ^= h >> 29; h *= 0xBF58476D1CE4E5B9ULL;
    h ^= h >> 32;
    return h;
}

// Reference runs under JAX default x64-disabled: astype(jnp.int64) -> int32,
// so key = ((c0*1024+c1)*1024+c2)*1024+c3 WRAPS mod 2^32. Truncation of the
// shifted value == two's-complement int32 overflow, bit-exact.
__device__ __forceinline__ uint make_key(int4 c) {
    return (uint)(((((((uint)c.x << 10) | (uint)c.y) << 10)
                    | (uint)c.z) << 10) | (uint)c.w);
}

// Insert (key32, idx) with min-index semantics for duplicate (mod-2^32) keys
// (matches stable argsort + searchsorted side='left' in the reference).
// entry = key32 << 24 | idx  (idx < 2^24), so same-key atomicMin == min-idx.
__global__ void build_table(const int4* __restrict__ coords, int n,
                            ull* __restrict__ tab, uint capmask) {
    int i = blockIdx.x * blockDim.x + threadIdx.x;
    if (i >= n) return;
    uint key = make_key(coords[i]);
    ull entry = ((ull)key << 24) | (ull)(uint)i;
    ull slot = mix_key(key) & capmask;
    while (true) {
        ull prev = atomicCAS(&tab[slot], EMPTY_ENTRY, entry);
        if (prev == EMPTY_ENTRY) return;            // claimed empty slot
        if ((uint)(prev >> 24) == key) {            // same key: keep min idx
            atomicMin(&tab[slot], entry);
            return;
        }
        slot = (slot + 1) & capmask;                // linear probe
    }
}

__device__ __forceinline__ int table_lookup(const ull* __restrict__ tab,
                                            uint capmask, uint key) {
    ull slot = mix_key(key) & capmask;
    while (true) {
        ull e = tab[slot];
        if (e == EMPTY_ENTRY) return -1;
        if ((uint)(e >> 24) == key) return (int)(e & 0xFFFFFFULL);
        slot = (slot + 1) & capmask;
    }
}

// One wave handles 2 rows: lanes 0-31 -> row 2w, lanes 32-63 -> row 2w+1.
// Each lane handles a float2 of the 64-wide feature row -> every global
// access is a contiguous 512B/wave, 8B-aligned transaction (stride-66
// merged rows included: 66 and 66r+2 are even).
__global__ __launch_bounds__(256) void fused_kernel(
    const int4*   __restrict__ xc,
    const float2* __restrict__ xf2,     // x_feats viewed as [N,32] float2
    const float2* __restrict__ mscores, // mask_scores [M] float2
    const ull*    __restrict__ mtab, uint mmask,
    const ull*    __restrict__ dtab, uint dmask,
    float2* __restrict__ out0,          // x_pruned  [N,32] float2
    float2* __restrict__ out1,          // scaled    [N,32] float2
    float*  __restrict__ outm,          // merged    [N,66] float
    float*  __restrict__ outds,         // ds_mask   [Nd]
    int N) {
    int tid  = blockIdx.x * 256 + threadIdx.x;
    int w    = tid >> 6;
    int lane = threadIdx.x & 63;
    int row  = w * 2 + (lane >> 5);
    if (row >= N) return;
    int j = lane & 31;

    float s = 0.f, a = 0.f, m0 = 0.f, m1 = 0.f;
    if (j == 0) {   // lanes 0 and 32 probe concurrently (same SIMT path)
        int4 c = xc[row];
        uint xk = make_key(c);
        int mi = table_lookup(mtab, mmask, xk);
        if (mi >= 0) {
            float2 ms = mscores[mi];
            m0 = ms.x; m1 = ms.y;
            s = m1;                      // ExpandAs uses column 1
            if (s > 0.5f) a = 1.f;       // THRESH
        }
        if (a != 0.f) {                  // segment_max of binary attn == OR-scatter
            int4 p; p.x = c.x; p.y = c.y >> 1; p.z = c.z >> 1; p.w = c.w >> 1;
            int di = table_lookup(dtab, dmask, make_key(p));
            if (di >= 0) outds[di] = 1.0f;   // benign race: same value
        }
    }
    int src = lane & 32;   // broadcast from lane 0 / lane 32 to its half
    s  = __shfl(s,  src);
    a  = __shfl(a,  src);
    m0 = __shfl(m0, src);
    m1 = __shfl(m1, src);
    float sa = s * a;

    size_t fidx = (size_t)row * 32 + j;
    float2 f = xf2[fidx];
    float2 o0; o0.x = f.x * a;  o0.y = f.y * a;
    float2 o1; o1.x = f.x * sa; o1.y = f.y * sa;
    out0[fidx] = o0;
    out1[fidx] = o1;

    float* mrow = outm + (size_t)row * 66;
    *(float2*)(mrow + 2 + 2 * j) = f;    // merged cols 2..65 = x_feats
    if (j == 0) {
        float2 mm; mm.x = m0; mm.y = m1; // merged cols 0..1 = m_at_x
        *(float2*)mrow = mm;
    }
}

extern "C" void kernel_launch(void* const* d_in, const int* in_sizes, int n_in,
                              void* d_out, int out_size, void* d_ws, size_t ws_size,
                              hipStream_t stream) {
    const int4*  xc  = (const int4*)d_in[0];   // x_coords    [N,4] i32
    const float* xf  = (const float*)d_in[1];  // x_feats     [N,64] f32
    const int4*  mc  = (const int4*)d_in[2];   // mask_coords [M,4] i32
    const float* msc = (const float*)d_in[3];  // mask_scores [M,2] f32
    const int4*  dc  = (const int4*)d_in[4];   // ds_coords   [Nd,4] i32

    int N  = in_sizes[0] / 4;
    int M  = in_sizes[2] / 4;
    int Nd = in_sizes[4] / 4;

    // Hash table capacities (power of two). Preferred: 4M + 1M slots = 40 MB.
    size_t mcap = 1ull << 22;
    size_t dcap = 1ull << 20;
    while ((mcap + dcap) * sizeof(ull) > ws_size && mcap > (size_t)(2 * M) * 2 / 3)
        mcap >>= 1;   // floor ~2^21 for M=1.5M (load 0.72, still functional)
    while ((mcap + dcap) * sizeof(ull) > ws_size && dcap > (size_t)Nd * 2)
        dcap >>= 1;

    ull* mtab = (ull*)d_ws;
    ull* dtab = mtab + mcap;

    float* out0  = (float*)d_out;                 // x_pruned  N*64
    float* out1  = out0 + (size_t)N * 64;         // scaled    N*64
    float* outm  = out1 + (size_t)N * 64;         // merged    N*66
    float* outds = outm + (size_t)N * 66;         // ds_mask   Nd

    // ws and out are re-poisoned (0xAA) before every timed call -> rebuild/zero.
    hipMemsetAsync(d_ws, 0xFF, (mcap + dcap) * sizeof(ull), stream);
    hipMemsetAsync(outds, 0, (size_t)Nd * sizeof(float), stream);

    build_table<<<(M + 255) / 256, 256, 0, stream>>>(mc, M, mtab, (uint)(mcap - 1));
    build_table<<<(Nd + 255) / 256, 256, 0, stream>>>(dc, Nd, dtab, (uint)(dcap - 1));

    int waves  = (N + 1) / 2;           // 2 rows per wave
    int blocks = (waves + 3) / 4;       // 4 waves per 256-thread block
    fused_kernel<<<blocks, 256, 0, stream>>>(
        xc, (const float2*)xf, (const float2*)msc,
        mtab, (uint)(mcap - 1), dtab, (uint)(dcap - 1),
        (float2*)out0, (float2*)out1, outm, outds, N);
}